// Round 10
// baseline (330.778 us; speedup 1.0000x reference)
//
#include <hip/hip_runtime.h>
#include <hip/hip_cooperative_groups.h>
#include <math.h>

namespace cg = cooperative_groups;

#define M_   2049
#define B_   16
#define N_   1024
#define TAU_ 2.821e-5
#define PI_  3.14159265358979323846
#define TWO_PI_ 6.283185307179586476925286766559

#define GS_CH    16     // point-chunks per batch in the scatter spread (256 blocks)
#define CV_SPLIT 16     // mp-split for conv phase
#define FMM_LPP  16     // lanes per point in fmm phase
#define MPAD     2052   // padded m-stride for conv partials
#define NBLK     512    // cooperative grid size (2 blocks/CU)
#define NTHR     (NBLK * 256)

// LDS swizzle for the conv h-window: pad 1 double per 4 so the FIR
// lane-stride-4 read (word stride 8 -> 16-way conflict raw) becomes word
// stride 10 -> 4-way aliasing (~free).  [R7: conflicts 6.4M->76K]
#define SW(i) ((i) + ((i) >> 2))

// ---------------------------------------------------------------------------
// Single cooperative kernel; phases separated by grid.sync() (replaces 4
// inter-dispatch gaps — R9 post-mortem: controllable time is launch/gap
// dominated, not pipe-work dominated).
// ---------------------------------------------------------------------------
__global__ void __launch_bounds__(256, 2)
mega_kernel(const float* __restrict__ x,
            const float* __restrict__ s0, const float* __restrict__ a0,
            const float* __restrict__ s1, const float* __restrict__ a1,
            float* __restrict__ out,
            double* __restrict__ gsum, double* __restrict__ hhalf,
            double* __restrict__ part, double* __restrict__ gpart,
            double* __restrict__ conv) {
    cg::grid_group grid = cg::this_grid();
    // LDS union, sized for the conv phase: w0s[1456] + w1s[1456] + red[512]
    __shared__ double smem[3424];
    const int bx  = blockIdx.x;
    const int tid = threadIdx.x;

    // ======================= P1: spread (256 blocks) | h (5 blocks) =========
    if (bx < GS_CH * B_) {
        // ---- gsum scatter into LDS bins, plain store to private slice ----
        const int b  = bx >> 4;            // / GS_CH
        const int ch = bx & 15;
        for (int i = tid; i < M_; i += 256) smem[i] = 0.0;
        __syncthreads();
        const int pl  = tid >> 2;          // local point 0..63
        const int sub = tid & 3;           // quarter-window
        const double du      = TWO_PI_ / (double)M_;
        const double inv4tau = 1.0 / (4.0 * TAU_);
        const double u = (double)x[b * N_ + ch * (N_ / GS_CH) + pl] * (TWO_PI_ / 10.0);
        const int mc = (int)(u / du + 0.5);
        const int start = mc - 33 + sub * 17;      // 4x17 covers mc-33 .. mc+34
        for (int i = 0; i < 17; ++i) {
            int m = start + i;
            if (m >= 0 && m < M_) {
                double d = u - du * (double)m;
                double t = d * d * inv4tau;
                if (t < 88.0) atomicAdd(&smem[m], (double)__expf(-(float)t));
            }
        }
        __syncthreads();
        double* gp = gpart + ((size_t)ch * B_ + b) * M_;
        for (int i = tid; i < M_; i += 256) gp[i] = smem[i];
    } else if (bx < GS_CH * B_ + 5) {
        // ---- h via Chebyshev recurrence: c_{j+1} = 2 c1 c_j - c_{j-1} ----
        // (replaces the per-block 1025-entry f64 cos table; err ~1e-13 rel)
        const int dt = bx - GS_CH * B_;    // d-tile 0..4
        double* cf0 = smem;                // 1024 coeffs, channel 0
        double* cf1 = smem + 1024;         // 1024 coeffs, channel 1
        const double sA = 5.0 * (double)s0[0];
        const double sB = 5.0 * (double)s1[0];
        const double A0 = -(double)a0[0] * 4.0 * PI_;
        const double A1 =  (double)a1[0] * 4.0 * PI_;
        for (int j = tid + 1; j <= 1024; j += 256) {
            double k2   = (double)j * (double)j;
            double dec2 = (PI_ / TAU_) * exp(2.0 * TAU_ * k2);   // deconv^2
            double base = 2.0 * (10.0 / TWO_PI_) * dec2 / (double)M_;
            cf0[j - 1] = base * (A0 / (k2 + sA * sA));
            double den = k2 + sB * sB;
            cf1[j - 1] = base * (A1 / (den * den));
        }
        __syncthreads();
        const int d = dt * 256 + tid;
        if (d <= 1024) {
            const double w0base = (10.0 / TWO_PI_) * (PI_ / TAU_) / (double)M_;
            double acc0 = w0base * (A0 / (sA * sA));
            double acc1 = w0base * (A1 / ((sB * sB) * (sB * sB)));
            double c1    = cos(TWO_PI_ * (double)d / (double)M_);
            double twoc1 = 2.0 * c1;
            double cm1 = 1.0, c = c1;      // c_0, c_1
            #pragma unroll 4
            for (int j = 1; j <= 1024; ++j) {
                acc0 += cf0[j - 1] * c;
                acc1 += cf1[j - 1] * c;
                double cn = twoc1 * c - cm1;
                cm1 = c; c = cn;
            }
            hhalf[d]        = acc0;
            hhalf[1025 + d] = acc1;
        }
    }
    grid.sync();

    // ======================= P2: gsum fold ==================================
    {
        const int gid = bx * 256 + tid;
        if (gid < B_ * M_) {
            const size_t sstride = (size_t)B_ * M_;
            double acc = 0.0;
            #pragma unroll
            for (int k = 0; k < GS_CH; ++k) acc += gpart[(size_t)k * sstride + gid];
            gsum[gid] = acc;
        }
    }
    grid.sync();

    // ======================= P3: conv (all 512 blocks) ======================
    {
        double* w0s = smem;                // SW(1153) <= 1441
        double* w1s = smem + 1456;
        double* red = smem + 2912;         // 512
        const int mt = bx & 1;
        const int s  = (bx >> 1) & 15;
        const int b  = bx >> 5;
        const int m0  = mt * 1024;
        const int p0  = (s * M_) / CV_SPLIT;
        const int p1  = ((s + 1) * M_) / CV_SPLIT;
        const int len = p1 - p0;           // 128 or 129
        const int wcount = 1024 + len;
        int base = m0 - (p0 + len - 1);
        while (base < 0) base += M_;
        for (int i = tid; i < wcount; i += 256) {
            int idx = base + i;
            while (idx >= M_) idx -= M_;
            int d = (idx > 1024) ? (M_ - idx) : idx;   // h even
            w0s[SW(i)] = hhalf[d];
            w1s[SW(i)] = hhalf[1025 + d];
        }
        __syncthreads();

        const double* gs = gsum + (size_t)b * M_ + p0;   // wave-uniform -> s_load

        int q = 4 * tid + len - 1;
        double c0w0 = w0s[SW(q)],   c0w1 = w0s[SW(q+1)], c0w2 = w0s[SW(q+2)], c0w3 = w0s[SW(q+3)];
        double c1w0 = w1s[SW(q)],   c1w1 = w1s[SW(q+1)], c1w2 = w1s[SW(q+2)], c1w3 = w1s[SW(q+3)];
        double a00 = 0.0, a01 = 0.0, a02 = 0.0, a03 = 0.0;
        double a10 = 0.0, a11 = 0.0, a12 = 0.0, a13 = 0.0;
        #pragma unroll 4
        for (int t = 0; t < len; ++t) {
            double g = gs[t];
            a00 += g * c0w0; a01 += g * c0w1; a02 += g * c0w2; a03 += g * c0w3;
            a10 += g * c1w0; a11 += g * c1w1; a12 += g * c1w2; a13 += g * c1w3;
            c0w3 = c0w2; c0w2 = c0w1; c0w1 = c0w0;
            c1w3 = c1w2; c1w2 = c1w1; c1w1 = c1w0;
            --q;
            c0w0 = w0s[SW(q)]; c1w0 = w1s[SW(q)];
        }
        {
            double* pv = part + (((size_t)s * B_ + b) * 2) * MPAD + m0 + 4 * tid;
            pv[0]        = a00; pv[1]        = a01; pv[2]        = a02; pv[3]        = a03;
            pv[MPAD + 0] = a10; pv[MPAD + 1] = a11; pv[MPAD + 2] = a12; pv[MPAD + 3] = a13;
        }
        if (mt == 1) {      // m = 2048 side-reduction (mt uniform per block)
            double t0 = 0.0, t1 = 0.0;
            if (tid < len) {
                double g = gs[tid];
                int qq = 1023 + len - tid;
                t0 = g * w0s[SW(qq)];
                t1 = g * w1s[SW(qq)];
            }
            red[tid]       = t0;
            red[256 + tid] = t1;
            __syncthreads();
            for (int off = 128; off > 0; off >>= 1) {
                if (tid < off) {
                    red[tid]       += red[tid + off];
                    red[256 + tid] += red[256 + tid + off];
                }
                __syncthreads();
            }
            if (tid == 0) {
                double* pv = part + (((size_t)s * B_ + b) * 2) * MPAD;
                pv[2048]        = red[0];
                pv[MPAD + 2048] = red[256];
            }
        }
    }
    grid.sync();

    // ======================= P4: part reduce ================================
    {
        const int idx = bx * 256 + tid;
        if (idx < B_ * 2 * M_) {
            const int b  = idx / (2 * M_);
            const int rm = idx - b * 2 * M_;
            const int c  = rm / M_;
            const int m  = rm - c * M_;
            const size_t off = ((size_t)b * 2 + c) * MPAD + m;
            const size_t sstride = (size_t)B_ * 2 * MPAD;
            double acc = 0.0;
            #pragma unroll
            for (int k = 0; k < CV_SPLIT; ++k)
                acc += part[(size_t)k * sstride + off];
            conv[idx] = acc;
        }
    }
    grid.sync();

    // ======================= P5: fmm ========================================
    {
        const int gid = bx * 256 + tid;
        const double du      = TWO_PI_ / (double)M_;
        const double inv4tau = 1.0 / (4.0 * TAU_);
        #pragma unroll
        for (int it = 0; it < (B_ * N_ * FMM_LPP) / NTHR; ++it) {
            const int unit = gid + it * NTHR;
            const int pt  = unit / FMM_LPP;
            const int sub = unit & (FMM_LPP - 1);
            const int b   = pt >> 10;
            const double u = (double)x[pt] * (TWO_PI_ / 10.0);
            int mc = (int)(u / du + 0.5);
            int lo = mc - 34; if (lo < 0) lo = 0;
            int hi = mc + 34; if (hi > M_ - 1) hi = M_ - 1;
            const double* c0 = conv + (size_t)(b * 2) * M_;
            const double* c1 = c0 + M_;
            double a0v = 0.0, a1v = 0.0;
            for (int m = lo + sub; m <= hi; m += FMM_LPP) {
                double d = u - du * (double)m;
                double g = (double)__expf(-(float)(d * d * inv4tau));
                a0v += g * c0[m];
                a1v += g * c1[m];
            }
            a0v += __shfl_xor(a0v, 1); a1v += __shfl_xor(a1v, 1);
            a0v += __shfl_xor(a0v, 2); a1v += __shfl_xor(a1v, 2);
            a0v += __shfl_xor(a0v, 4); a1v += __shfl_xor(a1v, 4);
            a0v += __shfl_xor(a0v, 8); a1v += __shfl_xor(a1v, 8);
            if (sub == 0) {
                out[pt * 2 + 0] = (float)(a0v / (double)M_);
                out[pt * 2 + 1] = (float)(a1v / (double)M_);
            }
        }
    }
}

// ---------------------------------------------------------------------------
extern "C" void kernel_launch(void* const* d_in, const int* in_sizes, int n_in,
                              void* d_out, int out_size, void* d_ws, size_t ws_size,
                              hipStream_t stream) {
    (void)in_sizes; (void)n_in; (void)out_size; (void)ws_size;
    const float* x  = (const float*)d_in[0];
    const float* s0 = (const float*)d_in[1];
    const float* a0 = (const float*)d_in[2];
    const float* s1 = (const float*)d_in[3];
    const float* a1 = (const float*)d_in[4];
    float* out = (float*)d_out;

    // Workspace layout (f64); every cell plainly overwritten each call.
    double* gsum  = (double*)d_ws;                            // B*M      = 32784
    double* hhalf = gsum + B_ * M_;                           // 2*1025   = 2050
    double* conv  = hhalf + 2 * 1025;                         // B*2*M    = 65568
    double* part  = conv + B_ * 2 * M_;                       // 16*B*2*MPAD = 1050624
    double* gpart = part + (size_t)CV_SPLIT * B_ * 2 * MPAD;  // GS_CH*B*M = 524544

    void* args[] = { (void*)&x, (void*)&s0, (void*)&a0, (void*)&s1, (void*)&a1,
                     (void*)&out, (void*)&gsum, (void*)&hhalf, (void*)&part,
                     (void*)&gpart, (void*)&conv };
    hipLaunchCooperativeKernel((const void*)mega_kernel, dim3(NBLK), dim3(256),
                               args, 0, stream);
}

// Round 12
// 113.900 us; speedup vs baseline: 2.9041x; 2.9041x over previous
//
#include <hip/hip_runtime.h>
#include <math.h>

#define M_   2049
#define B_   16
#define N_   1024
#define TAU_ 2.821e-5
#define PI_  3.14159265358979323846
#define TWO_PI_ 6.283185307179586476925286766559

#define GS_CH    8      // point-chunks per batch in the scatter spread (128 blocks)
#define H_JSPLIT 8      // j-chunks of 128 for the Chebyshev h part (40 blocks)
#define CV_SPLIT 8      // mp-split for conv (256 blocks)
#define MPAD     2052   // padded m-stride for conv partials

// LDS swizzle for the conv h-window: pad 1 double per 4 so the FIR
// lane-stride-4 read (word stride 8 -> 16-way conflict raw) becomes word
// stride 10 -> 4-way aliasing (~free).  [R7: conflicts 6.4M->76K]
#define SW(i) ((i) + ((i) >> 2))

// NOTE (R10 post-mortem): cooperative grid.sync() measured ~60us each at 512
// blocks on MI355X (9.2 GB of sync-flag refetch across non-coherent XCD L2s).
// Multi-kernel dispatch boundaries in the captured graph are far cheaper.
// NOTE (R11 post-mortem): with CV_SPLIT=8, len can be 257 > blockDim; the
// m=2048 side-reduction MUST stride over taps (dropped tap = 1.8e21 error).

// ---------------------------------------------------------------------------
// Kernel 1:
//  blocks [0,128):   gsum scatter into LDS bins, plain store to gpart[ch].
//  blocks [128,168): h via per-chunk Chebyshev recurrence
//    cos((j+1)t) = 2cos(t)cos(jt) - cos((j-1)t)  (3 f64 cos per thread);
//    plain store to hpart[jc].
// ---------------------------------------------------------------------------
__global__ void spread_h_kernel(const float* __restrict__ x,
                                const float* __restrict__ s0, const float* __restrict__ a0,
                                const float* __restrict__ s1, const float* __restrict__ a1,
                                double* __restrict__ gpart, double* __restrict__ hpart) {
    __shared__ double smem[M_ + 64];
    const int bx  = blockIdx.x;
    const int tid = threadIdx.x;

    if (bx < GS_CH * B_) {
        // ---- gsum scatter ----
        const int b  = bx / GS_CH;
        const int ch = bx % GS_CH;
        for (int i = tid; i < M_; i += 256) smem[i] = 0.0;
        __syncthreads();
        const int pl  = tid >> 1;          // local point 0..127
        const int sub = tid & 1;           // half-window 0/1
        const double du      = TWO_PI_ / (double)M_;
        const double inv4tau = 1.0 / (4.0 * TAU_);
        const double u = (double)x[b * N_ + ch * (N_ / GS_CH) + pl] * (TWO_PI_ / 10.0);
        const int mc = (int)(u / du + 0.5);
        const int start = mc - 33 + sub * 34;      // covers mc-33 .. mc+34
        for (int i = 0; i < 34; ++i) {
            int m = start + i;
            if (m >= 0 && m < M_) {
                double d = u - du * (double)m;
                double t = d * d * inv4tau;
                if (t < 88.0) atomicAdd(&smem[m], (double)__expf(-(float)t));
            }
        }
        __syncthreads();
        double* gp = gpart + ((size_t)ch * B_ + b) * M_;
        for (int i = tid; i < M_; i += 256) gp[i] = smem[i];
    } else {
        // ---- h part, Chebyshev per 128-j chunk, both channels ----
        const int t  = bx - GS_CH * B_;    // 0..39
        const int dt = t % 5;              // d-tile 0..4
        const int jc = t / 5;              // j-chunk 0..7
        const int jlo = 1 + jc * 128;
        double* cf0 = smem;                // 128 coeffs, channel 0
        double* cf1 = smem + 128;          // 128 coeffs, channel 1
        const double sA = 5.0 * (double)s0[0];
        const double sB = 5.0 * (double)s1[0];
        const double A0 = -(double)a0[0] * 4.0 * PI_;
        const double A1 =  (double)a1[0] * 4.0 * PI_;
        if (tid < 128) {
            int j = jlo + tid;
            double k2   = (double)j * (double)j;
            double dec2 = (PI_ / TAU_) * exp(2.0 * TAU_ * k2);   // deconv^2
            double base = 2.0 * (10.0 / TWO_PI_) * dec2 / (double)M_;
            cf0[tid] = base * (A0 / (k2 + sA * sA));
            double den = k2 + sB * sB;
            cf1[tid] = base * (A1 / (den * den));
        }
        __syncthreads();
        const int d = dt * 256 + tid;
        if (d <= 1024) {
            double acc0 = 0.0, acc1 = 0.0;
            if (jc == 0) {   // j = 0 term, added once per channel
                double w0base = (10.0 / TWO_PI_) * (PI_ / TAU_) / (double)M_;
                acc0 = w0base * (A0 / (sA * sA));
                acc1 = w0base * (A1 / ((sB * sB) * (sB * sB)));
            }
            const double theta = TWO_PI_ * (double)d / (double)M_;
            const double twoc1 = 2.0 * cos(theta);
            double cm1 = cos((double)(jlo - 1) * theta);
            double c   = cos((double)jlo * theta);
            #pragma unroll 4
            for (int jj = 0; jj < 128; ++jj) {
                acc0 += cf0[jj] * c;
                acc1 += cf1[jj] * c;
                double cn = fma(twoc1, c, -cm1);
                cm1 = c; c = cn;
            }
            double* hp = hpart + (size_t)jc * 2050;
            hp[d]        = acc0;
            hp[1025 + d] = acc1;
        }
    }
}

// ---------------------------------------------------------------------------
// Kernel 2: gsum[b][m] = sum_ch gpart[ch][b][m];  hhalf = sum_jc hpart[jc].
// ---------------------------------------------------------------------------
__global__ void gred_kernel(const double* __restrict__ gpart, const double* __restrict__ hpart,
                            double* __restrict__ gsum, double* __restrict__ hhalf) {
    const int idx = blockIdx.x * 256 + threadIdx.x;
    if (idx < B_ * M_) {
        const size_t sstride = (size_t)B_ * M_;
        double acc = 0.0;
        #pragma unroll
        for (int k = 0; k < GS_CH; ++k) acc += gpart[(size_t)k * sstride + idx];
        gsum[idx] = acc;
    } else if (idx < B_ * M_ + 2050) {
        const int e = idx - B_ * M_;
        double acc = 0.0;
        #pragma unroll
        for (int k = 0; k < H_JSPLIT; ++k) acc += hpart[(size_t)k * 2050 + e];
        hhalf[e] = acc;
    }
}

// ---------------------------------------------------------------------------
// Kernel 3: part[s][b][c][m] = sum over mp-chunk s of gsum[b][mp]*h_c[(m-mp)%M]
// FIR register-sliding-window, swizzled LDS window; R=4 consecutive m per
// lane, both channels; plain coalesced stores to a private partial slice.
// ---------------------------------------------------------------------------
__global__ void conv_kernel(const double* __restrict__ gsum, const double* __restrict__ hhalf,
                            double* __restrict__ part) {
    __shared__ double w0s[1604];        // SW(1280) = 1600 max index
    __shared__ double w1s[1604];
    __shared__ double red[512];
    const int mt = blockIdx.x;          // 0 or 1
    const int s  = blockIdx.y;          // mp-chunk 0..7
    const int b  = blockIdx.z;
    const int m0  = mt * 1024;
    const int p0  = (s * M_) / CV_SPLIT;
    const int p1  = ((s + 1) * M_) / CV_SPLIT;
    const int len = p1 - p0;            // 256 or 257
    const int wcount = 1024 + len;
    int base = m0 - (p0 + len - 1);
    while (base < 0) base += M_;
    for (int i = threadIdx.x; i < wcount; i += 256) {
        int idx = base + i;
        while (idx >= M_) idx -= M_;
        int d = (idx > 1024) ? (M_ - idx) : idx;   // h even
        w0s[SW(i)] = hhalf[d];
        w1s[SW(i)] = hhalf[1025 + d];
    }
    __syncthreads();

    const double* gs = gsum + (size_t)b * M_ + p0;   // wave-uniform -> s_load

    int q = 4 * threadIdx.x + len - 1;
    double c0w0 = w0s[SW(q)],   c0w1 = w0s[SW(q+1)], c0w2 = w0s[SW(q+2)], c0w3 = w0s[SW(q+3)];
    double c1w0 = w1s[SW(q)],   c1w1 = w1s[SW(q+1)], c1w2 = w1s[SW(q+2)], c1w3 = w1s[SW(q+3)];
    double a00 = 0.0, a01 = 0.0, a02 = 0.0, a03 = 0.0;
    double a10 = 0.0, a11 = 0.0, a12 = 0.0, a13 = 0.0;
    #pragma unroll 4
    for (int t = 0; t < len; ++t) {
        double g = gs[t];
        a00 += g * c0w0; a01 += g * c0w1; a02 += g * c0w2; a03 += g * c0w3;
        a10 += g * c1w0; a11 += g * c1w1; a12 += g * c1w2; a13 += g * c1w3;
        c0w3 = c0w2; c0w2 = c0w1; c0w1 = c0w0;
        c1w3 = c1w2; c1w2 = c1w1; c1w1 = c1w0;
        --q;
        c0w0 = w0s[SW(q)]; c1w0 = w1s[SW(q)];
    }
    {
        double* pv = part + (((size_t)s * B_ + b) * 2) * MPAD + m0 + 4 * threadIdx.x;
        pv[0]        = a00; pv[1]        = a01; pv[2]        = a02; pv[3]        = a03;
        pv[MPAD + 0] = a10; pv[MPAD + 1] = a11; pv[MPAD + 2] = a12; pv[MPAD + 3] = a13;
    }
    if (mt == 1) {      // m = 2048 side-reduction (mt uniform per block)
        // R11 bugfix: stride over taps — len can be 257 > blockDim.
        double t0 = 0.0, t1 = 0.0;
        for (int mp = threadIdx.x; mp < len; mp += 256) {
            double g = gs[mp];
            int qq = 1023 + len - mp;
            t0 += g * w0s[SW(qq)];
            t1 += g * w1s[SW(qq)];
        }
        red[threadIdx.x]       = t0;
        red[256 + threadIdx.x] = t1;
        __syncthreads();
        for (int off = 128; off > 0; off >>= 1) {
            if (threadIdx.x < off) {
                red[threadIdx.x]       += red[threadIdx.x + off];
                red[256 + threadIdx.x] += red[256 + threadIdx.x + off];
            }
            __syncthreads();
        }
        if (threadIdx.x == 0) {
            double* pv = part + (((size_t)s * B_ + b) * 2) * MPAD;
            pv[2048]        = red[0];
            pv[MPAD + 2048] = red[256];
        }
    }
}

// ---------------------------------------------------------------------------
// Kernel 4: fmm with inline part-fold.  64 blocks = B x 4 point-chunks.
// Each block folds the 8 part slices for its batch (f64 accumulators) into an
// f32 LDS copy of conv[b] (f32 error ~1e15 abs << 6.6e18 threshold), then 16
// lanes/point sample the +-34-bin window from LDS.
// ---------------------------------------------------------------------------
__global__ void fmm_kernel(const float* __restrict__ x, const double* __restrict__ part,
                           float* __restrict__ out) {
    __shared__ float cf[2 * M_];
    const int b  = blockIdx.x >> 2;
    const int pc = blockIdx.x & 3;     // point-chunk of 256
    const int tid = threadIdx.x;
    const size_t sstride = (size_t)B_ * 2 * MPAD;
    for (int i = tid; i < 2 * M_; i += 256) {
        const int c = (i >= M_) ? 1 : 0;
        const int m = i - c * M_;
        const size_t off = ((size_t)b * 2 + c) * MPAD + m;
        double acc = 0.0;
        #pragma unroll
        for (int k = 0; k < CV_SPLIT; ++k)
            acc += part[(size_t)k * sstride + off];
        cf[i] = (float)acc;
    }
    __syncthreads();

    const int sub = tid & 15;          // lane within point-group
    const int pl  = tid >> 4;          // point 0..15 within pass
    const double du      = TWO_PI_ / (double)M_;
    const double inv4tau = 1.0 / (4.0 * TAU_);
    #pragma unroll 2
    for (int pass = 0; pass < 16; ++pass) {
        const int pt = b * N_ + pc * 256 + pass * 16 + pl;
        const double u = (double)x[pt] * (TWO_PI_ / 10.0);
        int mc = (int)(u / du + 0.5);
        int lo = mc - 34; if (lo < 0) lo = 0;
        int hi = mc + 34; if (hi > M_ - 1) hi = M_ - 1;
        double a0v = 0.0, a1v = 0.0;
        for (int m = lo + sub; m <= hi; m += 16) {
            double d = u - du * (double)m;
            float g = __expf(-(float)(d * d * inv4tau));
            a0v += (double)(g * cf[m]);
            a1v += (double)(g * cf[M_ + m]);
        }
        a0v += __shfl_xor(a0v, 1); a1v += __shfl_xor(a1v, 1);
        a0v += __shfl_xor(a0v, 2); a1v += __shfl_xor(a1v, 2);
        a0v += __shfl_xor(a0v, 4); a1v += __shfl_xor(a1v, 4);
        a0v += __shfl_xor(a0v, 8); a1v += __shfl_xor(a1v, 8);
        if (sub == 0) {
            out[pt * 2 + 0] = (float)(a0v / (double)M_);
            out[pt * 2 + 1] = (float)(a1v / (double)M_);
        }
    }
}

// ---------------------------------------------------------------------------
extern "C" void kernel_launch(void* const* d_in, const int* in_sizes, int n_in,
                              void* d_out, int out_size, void* d_ws, size_t ws_size,
                              hipStream_t stream) {
    (void)in_sizes; (void)n_in; (void)out_size; (void)ws_size;
    const float* x  = (const float*)d_in[0];
    const float* s0 = (const float*)d_in[1];
    const float* a0 = (const float*)d_in[2];
    const float* s1 = (const float*)d_in[3];
    const float* a1 = (const float*)d_in[4];
    float* out = (float*)d_out;

    // Workspace layout (f64); every cell plainly overwritten each call (~6.7 MB).
    double* gsum  = (double*)d_ws;                            // B*M          = 32784
    double* hhalf = gsum + B_ * M_;                           // 2*1025       = 2050
    double* part  = hhalf + 2 * 1025;                         // 8*B*2*MPAD   = 525312
    double* gpart = part + (size_t)CV_SPLIT * B_ * 2 * MPAD;  // GS_CH*B*M    = 262272
    double* hpart = gpart + (size_t)GS_CH * B_ * M_;          // H_JSPLIT*2050= 16400

    hipLaunchKernelGGL(spread_h_kernel, dim3(GS_CH * B_ + 5 * H_JSPLIT), dim3(256), 0,
                       stream, x, s0, a0, s1, a1, gpart, hpart);
    hipLaunchKernelGGL(gred_kernel, dim3((B_ * M_ + 2050 + 255) / 256), dim3(256), 0,
                       stream, gpart, hpart, gsum, hhalf);
    hipLaunchKernelGGL(conv_kernel, dim3(2, CV_SPLIT, B_), dim3(256), 0, stream,
                       gsum, hhalf, part);
    hipLaunchKernelGGL(fmm_kernel, dim3(B_ * 4), dim3(256), 0, stream,
                       x, part, out);
}